// Round 5
// baseline (955.475 us; speedup 1.0000x reference)
//
#include <hip/hip_runtime.h>

#define N_NODES 500000
#define N_EDGES 8000000
#define N_PP    100000
#define TOTAL_E 150000
#define NUP     (TOTAL_E - N_PP)   // 50000
#define DIM     256
#define NB_STAT 256                // histogram slab blocks
#define SPB     4                  // segments per block in pool kernel
#define BN_EPS  1e-5

// ---- K2: edge messages + atomic scatter-add into aggr --------------------
__global__ __launch_bounds__(256) void k_edges(const float* __restrict__ x,
        const int* __restrict__ ei, const float* __restrict__ ea,
        const float* __restrict__ We, const float* __restrict__ be,
        float* __restrict__ aggr) {
    int t = blockIdx.x * 256 + threadIdx.x;
    const int nt = N_EDGES / 4;
    if (t >= nt) return;
    float we0 = We[0], we1 = We[1], b = be[0];
    int4 s4 = ((const int4*)ei)[t];
    int4 d4 = ((const int4*)(ei + N_EDGES))[t];
    float4 a0 = ((const float4*)ea)[2 * t];
    float4 a1 = ((const float4*)ea)[2 * t + 1];
    float m0 = x[s4.x] + we0 * a0.x + we1 * a0.y + b;
    float m1 = x[s4.y] + we0 * a0.z + we1 * a0.w + b;
    float m2 = x[s4.z] + we0 * a1.x + we1 * a1.y + b;
    float m3 = x[s4.w] + we0 * a1.z + we1 * a1.w + b;
    atomicAdd(&aggr[d4.x], fmaxf(m0, 0.f));
    atomicAdd(&aggr[d4.y], fmaxf(m1, 0.f));
    atomicAdd(&aggr[d4.z], fmaxf(m2, 0.f));
    atomicAdd(&aggr[d4.w], fmaxf(m3, 0.f));
}

// ---- K3: sort breakpoints, build piecewise-linear tables A,B [257][256] --
__global__ __launch_bounds__(256) void k_table(const float* __restrict__ w1,
        const float* __restrict__ b1, const float* __restrict__ w2,
        const float* __restrict__ b2, float* __restrict__ tsort,
        float* __restrict__ A, float* __restrict__ B) {
    __shared__ float key[256];
    __shared__ int   idx[256];
    __shared__ float w1s[256], b1s[256];
    int tid = threadIdx.x;
    float w = w1[tid], bb = b1[tid];
    w1s[tid] = w; b1s[tid] = bb;
    key[tid] = (w != 0.f) ? (-bb / w) : 3.4e38f;  // w==0: never crossed
    idx[tid] = tid;
    __syncthreads();
    // bitonic sort ascending (key, idx); one thread per pair, sync each step
    for (int k = 2; k <= 256; k <<= 1) {
        for (int j = k >> 1; j > 0; j >>= 1) {
            int ixj = tid ^ j;
            if (ixj > tid) {
                bool up = ((tid & k) == 0);
                float ka = key[tid], kb = key[ixj];
                if ((ka > kb) == up) {
                    key[tid] = kb; key[ixj] = ka;
                    int tmp = idx[tid]; idx[tid] = idx[ixj]; idx[ixj] = tmp;
                }
            }
            __syncthreads();
        }
    }
    tsort[tid] = key[tid];
    // A0,B0 for z -> -inf: active set = {w1<0}; w1==0 contributes relu(b1)
    int f = tid;
    float a = 0.f, bv = b2[f];
    for (int k = 0; k < 256; ++k) {
        float wk = w1s[k], bk = b1s[k];
        float w2kf = w2[k * DIM + f];
        if (wk < 0.f)                       { a += wk * w2kf; bv += bk * w2kf; }
        else if (wk == 0.f && bk > 0.f)     { bv += bk * w2kf; }
    }
    A[f] = a; B[f] = bv;
    // prefix scan over sorted breakpoints: crossing toggles unit idx[j]
    for (int j = 0; j < 256; ++j) {
        int k = idx[j];
        float wk = w1s[k], bk = b1s[k];
        float w2kf = w2[k * DIM + f];
        float cA = fabsf(wk);                                    // +w (act) / -w (deact)
        float cB = (wk > 0.f) ? bk : ((wk < 0.f) ? -bk : 0.f);
        a  += cA * w2kf;
        bv += cB * w2kf;
        A[(j + 1) * DIM + f] = a;
        B[(j + 1) * DIM + f] = bv;
    }
}

// ---- K4: per-node z, interval index, per-block {C,S1,S2} histograms ------
// Wave-uniform fast path: almost every node lands in the same interval
// (breakpoints cluster near 0, z ~ 7), so per-lane LDS atomics would be a
// 64-way same-address conflict. Reduce across the wave, 1 atomic per wave.
__global__ __launch_bounds__(256) void k_stats(const float* __restrict__ x,
        const float* __restrict__ aggr, const float* __restrict__ tsort,
        float* __restrict__ z, unsigned short* __restrict__ jidx,
        unsigned int* __restrict__ Cslab, float* __restrict__ S1slab,
        float* __restrict__ S2slab) {
    __shared__ float t[256];
    __shared__ unsigned int hc[257];
    __shared__ float h1[257], h2[257];
    int tid = threadIdx.x;
    t[tid] = tsort[tid];
    hc[tid] = 0u; h1[tid] = 0.f; h2[tid] = 0.f;
    if (tid == 0) { hc[256] = 0u; h1[256] = 0.f; h2[256] = 0.f; }
    __syncthreads();
    for (int base = blockIdx.x * 256; base < N_NODES; base += gridDim.x * 256) {
        int i = base + tid;
        bool valid = (i < N_NODES);
        float zi = 0.f;
        int lo = 0;
        if (valid) {
            zi = x[i] + aggr[i];
            z[i] = zi;
            int l = 0, h = 256;
            while (l < h) { int mid = (l + h) >> 1; if (t[mid] <= zi) l = mid + 1; else h = mid; }
            lo = l;
            jidx[i] = (unsigned short)lo;
        }
        int lo0 = __shfl(lo, 0);
        if (__all(valid) && __all(lo == lo0)) {
            float s1 = zi, s2 = zi * zi;
            #pragma unroll
            for (int o = 32; o; o >>= 1) {
                s1 += __shfl_xor(s1, o);
                s2 += __shfl_xor(s2, o);
            }
            if ((tid & 63) == 0) {
                atomicAdd(&hc[lo0], 64u);
                atomicAdd(&h1[lo0], s1);
                atomicAdd(&h2[lo0], s2);
            }
        } else if (valid) {
            atomicAdd(&hc[lo], 1u);
            atomicAdd(&h1[lo], zi);
            atomicAdd(&h2[lo], zi * zi);
        }
    }
    __syncthreads();
    int b = blockIdx.x;
    for (int m = tid; m < 257; m += 256) {
        Cslab[b * 257 + m]  = hc[m];
        S1slab[b * 257 + m] = h1[m];
        S2slab[b * 257 + m] = h2[m];
    }
}

// ---- K5: reduce histograms, exact mean/var per feature, BN scale/shift ---
__global__ __launch_bounds__(256) void k_finalize(
        const unsigned int* __restrict__ Cslab, const float* __restrict__ S1slab,
        const float* __restrict__ S2slab, const float* __restrict__ A,
        const float* __restrict__ B, const float* __restrict__ gamma,
        const float* __restrict__ beta, float* __restrict__ scale,
        float* __restrict__ shift) {
    __shared__ double hc[257], h1[257], h2[257];
    int tid = threadIdx.x;
    for (int m = tid; m < 257; m += 256) {
        double c = 0, s1 = 0, s2 = 0;
        for (int b = 0; b < NB_STAT; ++b) {
            c  += (double)Cslab[b * 257 + m];
            s1 += (double)S1slab[b * 257 + m];
            s2 += (double)S2slab[b * 257 + m];
        }
        hc[m] = c; h1[m] = s1; h2[m] = s2;
    }
    __syncthreads();
    int f = tid;
    double mean = 0, m2 = 0;
    for (int j = 0; j <= 256; ++j) {
        double a = (double)A[j * DIM + f], b = (double)B[j * DIM + f];
        mean += a * h1[j] + b * hc[j];
        m2   += a * a * h2[j] + 2.0 * a * b * h1[j] + b * b * hc[j];
    }
    mean /= (double)N_NODES;
    double var = m2 / (double)N_NODES - mean * mean;
    float sc = gamma[f] * (float)(1.0 / sqrt(var + BN_EPS));
    scale[f] = sc;
    shift[f] = beta[f] - (float)mean * sc;
}

// ---- K6a: fill the 50000 "up" rows with up_emb ---------------------------
__global__ __launch_bounds__(256) void k_upfill(const float* __restrict__ up,
        float* __restrict__ out) {
    __shared__ float4 u4[64];
    if (threadIdx.x < 64) u4[threadIdx.x] = ((const float4*)up)[threadIdx.x];
    __syncthreads();
    const long total = (long)NUP * 64;   // float4 slots
    for (long i = blockIdx.x * 256L + threadIdx.x; i < total; i += (long)gridDim.x * 256) {
        ((float4*)out)[i] = u4[i & 63];
    }
}

// ---- K6b: per-segment pooled BN+ReLU output (sorted segments, no atomics)
__global__ __launch_bounds__(256) void k_pool(const int* __restrict__ seg,
        const float* __restrict__ z, const unsigned short* __restrict__ jidx,
        const float* __restrict__ A, const float* __restrict__ B,
        const float* __restrict__ scale, const float* __restrict__ shift,
        float* __restrict__ out) {
    int p0 = blockIdx.x * SPB;
    int f = threadIdx.x;
    // lower_bound(seg, p0) — uniform across the block (broadcast loads)
    int lo = 0, hi = N_NODES;
    while (lo < hi) { int mid = (lo + hi) >> 1; if (seg[mid] < p0) lo = mid + 1; else hi = mid; }
    int i = lo;
    float sc = scale[f], sh = shift[f];
    for (int p = p0; p < p0 + SPB; ++p) {
        float acc = 0.f;
        while (i < N_NODES && seg[i] == p) {
            float zi = z[i];
            int j = (int)jidx[i];
            float h = sc * fmaf(A[j * DIM + f], zi, B[j * DIM + f]) + sh;
            acc += fmaxf(h, 0.f);
            ++i;
        }
        out[(long)(NUP + p) * DIM + f] = acc;
    }
}

extern "C" void kernel_launch(void* const* d_in, const int* in_sizes, int n_in,
                              void* d_out, int out_size, void* d_ws, size_t ws_size,
                              hipStream_t stream) {
    const float* x     = (const float*)d_in[0];
    const int*   ei    = (const int*)d_in[1];
    const float* ea    = (const float*)d_in[2];
    const int*   seg   = (const int*)d_in[3];
    // d_in[4] = total_edges (fixed 150000 by setup)
    const float* We    = (const float*)d_in[5];
    const float* be    = (const float*)d_in[6];
    const float* w1    = (const float*)d_in[7];
    const float* b1    = (const float*)d_in[8];
    const float* w2    = (const float*)d_in[9];
    const float* b2    = (const float*)d_in[10];
    const float* gamma = (const float*)d_in[11];
    const float* beta  = (const float*)d_in[12];
    const float* up    = (const float*)d_in[13];
    float* out = (float*)d_out;

    char* ws = (char*)d_ws;
    size_t off = 0;
    auto carve = [&](size_t bytes) -> void* {
        void* p = ws + off;
        off = (off + bytes + 255) & ~(size_t)255;
        return p;
    };
    float*          aggr   = (float*)carve(N_NODES * 4);
    float*          zbuf   = (float*)carve(N_NODES * 4);
    unsigned short* jidx   = (unsigned short*)carve(N_NODES * 2);
    float*          tsort  = (float*)carve(256 * 4);
    float*          A      = (float*)carve(257 * DIM * 4);
    float*          B      = (float*)carve(257 * DIM * 4);
    unsigned int*   Cslab  = (unsigned int*)carve(NB_STAT * 257 * 4);
    float*          S1slab = (float*)carve(NB_STAT * 257 * 4);
    float*          S2slab = (float*)carve(NB_STAT * 257 * 4);
    float*          scale  = (float*)carve(256 * 4);
    float*          shift  = (float*)carve(256 * 4);

    hipMemsetAsync(aggr, 0, N_NODES * 4, stream);
    k_edges<<<(N_EDGES / 4 + 255) / 256, 256, 0, stream>>>(x, ei, ea, We, be, aggr);
    k_table<<<1, 256, 0, stream>>>(w1, b1, w2, b2, tsort, A, B);
    k_stats<<<NB_STAT, 256, 0, stream>>>(x, aggr, tsort, zbuf, jidx, Cslab, S1slab, S2slab);
    k_finalize<<<1, 256, 0, stream>>>(Cslab, S1slab, S2slab, A, B, gamma, beta, scale, shift);
    k_upfill<<<2048, 256, 0, stream>>>(up, out);
    k_pool<<<N_PP / SPB, 256, 0, stream>>>(seg, zbuf, jidx, A, B, scale, shift, out);
}

// Round 11
// 906.796 us; speedup vs baseline: 1.0537x; 1.0537x over previous
//
#include <hip/hip_runtime.h>

#define N_NODES 500000
#define N_EDGES 8000000
#define N_PP    100000
#define TOTAL_E 150000
#define NUP     (TOTAL_E - N_PP)   // 50000
#define DIM     256
#define NB_STAT 256                // histogram slab blocks
#define SPB     4                  // segments per block in pool kernel
#define NXCD    8
#define BN_EPS  1e-5

// Plain global_atomic_add_f32, no sc0/sc1 -> executes in the issuing XCD's
// local L2 (no coherence-point write-through). Safe ONLY because each replica
// is written exclusively by blocks on one XCD (replica = HW_REG_XCC_ID).
__device__ __forceinline__ void atomic_add_l2(float* p, float v) {
    asm volatile("global_atomic_add_f32 %0, %1, off" :: "v"(p), "v"(v) : "memory");
}

// ---- K2: edge messages + XCD-local atomic scatter into per-XCD replica ---
__global__ __launch_bounds__(256) void k_edges(const float* __restrict__ x,
        const int* __restrict__ ei, const float* __restrict__ ea,
        const float* __restrict__ We, const float* __restrict__ be,
        float* __restrict__ aggr8) {
    int t = blockIdx.x * 256 + threadIdx.x;
    const int nt = N_EDGES / 4;
    if (t >= nt) return;
    unsigned xcc;
    asm("s_getreg_b32 %0, hwreg(HW_REG_XCC_ID)" : "=s"(xcc));
    float* aggr = aggr8 + (size_t)(xcc & (NXCD - 1)) * N_NODES;
    float we0 = We[0], we1 = We[1], b = be[0];
    int4 s4 = ((const int4*)ei)[t];
    int4 d4 = ((const int4*)(ei + N_EDGES))[t];
    float4 a0 = ((const float4*)ea)[2 * t];
    float4 a1 = ((const float4*)ea)[2 * t + 1];
    float m0 = x[s4.x] + we0 * a0.x + we1 * a0.y + b;
    float m1 = x[s4.y] + we0 * a0.z + we1 * a0.w + b;
    float m2 = x[s4.z] + we0 * a1.x + we1 * a1.y + b;
    float m3 = x[s4.w] + we0 * a1.z + we1 * a1.w + b;
    atomic_add_l2(&aggr[d4.x], fmaxf(m0, 0.f));
    atomic_add_l2(&aggr[d4.y], fmaxf(m1, 0.f));
    atomic_add_l2(&aggr[d4.z], fmaxf(m2, 0.f));
    atomic_add_l2(&aggr[d4.w], fmaxf(m3, 0.f));
}

// ---- K3: sort breakpoints, build piecewise-linear tables A,B [257][256] --
__global__ __launch_bounds__(256) void k_table(const float* __restrict__ w1,
        const float* __restrict__ b1, const float* __restrict__ w2,
        const float* __restrict__ b2, float* __restrict__ tsort,
        float* __restrict__ A, float* __restrict__ B) {
    __shared__ float key[256];
    __shared__ int   idx[256];
    __shared__ float w1s[256], b1s[256];
    int tid = threadIdx.x;
    float w = w1[tid], bb = b1[tid];
    w1s[tid] = w; b1s[tid] = bb;
    key[tid] = (w != 0.f) ? (-bb / w) : 3.4e38f;  // w==0: never crossed
    idx[tid] = tid;
    __syncthreads();
    // bitonic sort ascending (key, idx)
    for (int k = 2; k <= 256; k <<= 1) {
        for (int j = k >> 1; j > 0; j >>= 1) {
            int ixj = tid ^ j;
            if (ixj > tid) {
                bool up = ((tid & k) == 0);
                float ka = key[tid], kb = key[ixj];
                if ((ka > kb) == up) {
                    key[tid] = kb; key[ixj] = ka;
                    int tmp = idx[tid]; idx[tid] = idx[ixj]; idx[ixj] = tmp;
                }
            }
            __syncthreads();
        }
    }
    tsort[tid] = key[tid];
    // A0,B0 for z -> -inf: active set = {w1<0}; w1==0 contributes relu(b1)
    int f = tid;
    float a = 0.f, bv = b2[f];
    for (int k = 0; k < 256; ++k) {
        float wk = w1s[k], bk = b1s[k];
        float w2kf = w2[k * DIM + f];
        if (wk < 0.f)                       { a += wk * w2kf; bv += bk * w2kf; }
        else if (wk == 0.f && bk > 0.f)     { bv += bk * w2kf; }
    }
    A[f] = a; B[f] = bv;
    // prefix scan over sorted breakpoints: crossing toggles unit idx[j]
    for (int j = 0; j < 256; ++j) {
        int k = idx[j];
        float wk = w1s[k], bk = b1s[k];
        float w2kf = w2[k * DIM + f];
        float cA = fabsf(wk);                                    // +w (act) / -w (deact)
        float cB = (wk > 0.f) ? bk : ((wk < 0.f) ? -bk : 0.f);
        a  += cA * w2kf;
        bv += cB * w2kf;
        A[(j + 1) * DIM + f] = a;
        B[(j + 1) * DIM + f] = bv;
    }
}

// ---- K3b: segstart[p] = lower_bound(seg, p), p in [0, N_PP] --------------
__global__ __launch_bounds__(256) void k_segstart(const int* __restrict__ seg,
        int* __restrict__ segstart) {
    int i = blockIdx.x * 256 + threadIdx.x;
    if (i >= N_NODES) return;
    int cur = seg[i];
    int prev = (i == 0) ? -1 : seg[i - 1];
    for (int p = prev + 1; p <= cur; ++p) segstart[p] = i;
    if (i == N_NODES - 1)
        for (int p = cur + 1; p <= N_PP; ++p) segstart[p] = N_NODES;
}

// ---- K4: z = x + sum(replicas), interval index, per-block histograms -----
__global__ __launch_bounds__(256) void k_stats(const float* __restrict__ x,
        const float* __restrict__ aggr8, const float* __restrict__ tsort,
        float* __restrict__ z, unsigned short* __restrict__ jidx,
        unsigned int* __restrict__ Cslab, float* __restrict__ S1slab,
        float* __restrict__ S2slab) {
    __shared__ float t[256];
    __shared__ unsigned int hc[257];
    __shared__ float h1[257], h2[257];
    int tid = threadIdx.x;
    t[tid] = tsort[tid];
    hc[tid] = 0u; h1[tid] = 0.f; h2[tid] = 0.f;
    if (tid == 0) { hc[256] = 0u; h1[256] = 0.f; h2[256] = 0.f; }
    __syncthreads();
    for (int base = blockIdx.x * 256; base < N_NODES; base += gridDim.x * 256) {
        int i = base + tid;
        bool valid = (i < N_NODES);
        float zi = 0.f;
        int lo = 0;
        if (valid) {
            zi = x[i];
            #pragma unroll
            for (int r = 0; r < NXCD; ++r) zi += aggr8[(size_t)r * N_NODES + i];
            z[i] = zi;
            int l = 0, h = 256;
            while (l < h) { int mid = (l + h) >> 1; if (t[mid] <= zi) l = mid + 1; else h = mid; }
            lo = l;
            jidx[i] = (unsigned short)lo;
        }
        int lo0 = __shfl(lo, 0);
        if (__all(valid) && __all(lo == lo0)) {
            float s1 = zi, s2 = zi * zi;
            #pragma unroll
            for (int o = 32; o; o >>= 1) {
                s1 += __shfl_xor(s1, o);
                s2 += __shfl_xor(s2, o);
            }
            if ((tid & 63) == 0) {
                atomicAdd(&hc[lo0], 64u);
                atomicAdd(&h1[lo0], s1);
                atomicAdd(&h2[lo0], s2);
            }
        } else if (valid) {
            atomicAdd(&hc[lo], 1u);
            atomicAdd(&h1[lo], zi);
            atomicAdd(&h2[lo], zi * zi);
        }
    }
    __syncthreads();
    int b = blockIdx.x;
    for (int m = tid; m < 257; m += 256) {
        Cslab[b * 257 + m]  = hc[m];
        S1slab[b * 257 + m] = h1[m];
        S2slab[b * 257 + m] = h2[m];
    }
}

// ---- K5: reduce histograms, exact mean/var per feature, BN scale/shift ---
__global__ __launch_bounds__(256) void k_finalize(
        const unsigned int* __restrict__ Cslab, const float* __restrict__ S1slab,
        const float* __restrict__ S2slab, const float* __restrict__ A,
        const float* __restrict__ B, const float* __restrict__ gamma,
        const float* __restrict__ beta, float* __restrict__ scale,
        float* __restrict__ shift) {
    __shared__ double hc[257], h1[257], h2[257];
    int tid = threadIdx.x;
    for (int m = tid; m < 257; m += 256) {
        double c = 0, s1 = 0, s2 = 0;
        for (int b = 0; b < NB_STAT; ++b) {
            c  += (double)Cslab[b * 257 + m];
            s1 += (double)S1slab[b * 257 + m];
            s2 += (double)S2slab[b * 257 + m];
        }
        hc[m] = c; h1[m] = s1; h2[m] = s2;
    }
    __syncthreads();
    int f = tid;
    double mean = 0, m2 = 0;
    for (int j = 0; j <= 256; ++j) {
        double a = (double)A[j * DIM + f], b = (double)B[j * DIM + f];
        mean += a * h1[j] + b * hc[j];
        m2   += a * a * h2[j] + 2.0 * a * b * h1[j] + b * b * hc[j];
    }
    mean /= (double)N_NODES;
    double var = m2 / (double)N_NODES - mean * mean;
    float sc = gamma[f] * (float)(1.0 / sqrt(var + BN_EPS));
    scale[f] = sc;
    shift[f] = beta[f] - (float)mean * sc;
}

// ---- K6a: fill the 50000 "up" rows with up_emb ---------------------------
__global__ __launch_bounds__(256) void k_upfill(const float* __restrict__ up,
        float* __restrict__ out) {
    __shared__ float4 u4[64];
    if (threadIdx.x < 64) u4[threadIdx.x] = ((const float4*)up)[threadIdx.x];
    __syncthreads();
    const long total = (long)NUP * 64;   // float4 slots
    for (long i = blockIdx.x * 256L + threadIdx.x; i < total; i += (long)gridDim.x * 256) {
        ((float4*)out)[i] = u4[i & 63];
    }
}

// ---- K6b: per-segment pooled BN+ReLU output (segstart ranges, no search) -
__global__ __launch_bounds__(256) void k_pool(const int* __restrict__ segstart,
        const float* __restrict__ z, const unsigned short* __restrict__ jidx,
        const float* __restrict__ A, const float* __restrict__ B,
        const float* __restrict__ scale, const float* __restrict__ shift,
        float* __restrict__ out) {
    int p0 = blockIdx.x * SPB;
    int f = threadIdx.x;
    float sc = scale[f], sh = shift[f];
    int i = segstart[p0];
    for (int p = p0; p < p0 + SPB; ++p) {
        int iend = segstart[p + 1];
        float acc = 0.f;
        for (; i < iend; ++i) {
            float zi = z[i];
            int j = (int)jidx[i];
            float h = sc * fmaf(A[j * DIM + f], zi, B[j * DIM + f]) + sh;
            acc += fmaxf(h, 0.f);
        }
        out[(long)(NUP + p) * DIM + f] = acc;
    }
}

extern "C" void kernel_launch(void* const* d_in, const int* in_sizes, int n_in,
                              void* d_out, int out_size, void* d_ws, size_t ws_size,
                              hipStream_t stream) {
    const float* x     = (const float*)d_in[0];
    const int*   ei    = (const int*)d_in[1];
    const float* ea    = (const float*)d_in[2];
    const int*   seg   = (const int*)d_in[3];
    // d_in[4] = total_edges (fixed 150000 by setup)
    const float* We    = (const float*)d_in[5];
    const float* be    = (const float*)d_in[6];
    const float* w1    = (const float*)d_in[7];
    const float* b1    = (const float*)d_in[8];
    const float* w2    = (const float*)d_in[9];
    const float* b2    = (const float*)d_in[10];
    const float* gamma = (const float*)d_in[11];
    const float* beta  = (const float*)d_in[12];
    const float* up    = (const float*)d_in[13];
    float* out = (float*)d_out;

    char* ws = (char*)d_ws;
    size_t off = 0;
    auto carve = [&](size_t bytes) -> void* {
        void* p = ws + off;
        off = (off + bytes + 255) & ~(size_t)255;
        return p;
    };
    float*          aggr8  = (float*)carve((size_t)NXCD * N_NODES * 4);  // 16 MB
    float*          zbuf   = (float*)carve(N_NODES * 4);
    unsigned short* jidx   = (unsigned short*)carve(N_NODES * 2);
    int*            segst  = (int*)carve((N_PP + 1) * 4);
    float*          tsort  = (float*)carve(256 * 4);
    float*          A      = (float*)carve(257 * DIM * 4);
    float*          B      = (float*)carve(257 * DIM * 4);
    unsigned int*   Cslab  = (unsigned int*)carve(NB_STAT * 257 * 4);
    float*          S1slab = (float*)carve(NB_STAT * 257 * 4);
    float*          S2slab = (float*)carve(NB_STAT * 257 * 4);
    float*          scale  = (float*)carve(256 * 4);
    float*          shift  = (float*)carve(256 * 4);

    hipMemsetAsync(aggr8, 0, (size_t)NXCD * N_NODES * 4, stream);
    k_edges<<<(N_EDGES / 4 + 255) / 256, 256, 0, stream>>>(x, ei, ea, We, be, aggr8);
    k_table<<<1, 256, 0, stream>>>(w1, b1, w2, b2, tsort, A, B);
    k_segstart<<<(N_NODES + 255) / 256, 256, 0, stream>>>(seg, segst);
    k_stats<<<NB_STAT, 256, 0, stream>>>(x, aggr8, tsort, zbuf, jidx, Cslab, S1slab, S2slab);
    k_finalize<<<1, 256, 0, stream>>>(Cslab, S1slab, S2slab, A, B, gamma, beta, scale, shift);
    k_upfill<<<2048, 256, 0, stream>>>(up, out);
    k_pool<<<N_PP / SPB, 256, 0, stream>>>(segst, zbuf, jidx, A, B, scale, shift, out);
}

// Round 15
// 704.926 us; speedup vs baseline: 1.3554x; 1.2864x over previous
//
#include <hip/hip_runtime.h>

#define N_NODES 500000
#define N_EDGES 8000000
#define N_PP    100000
#define TOTAL_E 150000
#define NUP     (TOTAL_E - N_PP)   // 50000
#define DIM     256
#define NB_STAT 256                // histogram slab blocks (k_stats)
#define SPB     4                  // segments per block in pool kernel
#define BN_EPS  1e-5

// binning parameters: 62 bins of 8192 nodes; 8 reduction replicas
#define BINSH   13
#define SLICE   8192
#define NBIN    62                 // ceil(500000 / 8192)
#define RREP    8
#define CHUNK   4096               // edges per k_scatter block
#define EPT     16                 // edges per thread (CHUNK/256)

// ---- K1a: exact per-bin histogram of dst ---------------------------------
__global__ __launch_bounds__(256) void k_count(const int* __restrict__ ei,
        int* __restrict__ bincnt) {
    __shared__ unsigned int h[4][NBIN];
    int tid = threadIdx.x;
    for (int m = tid; m < 4 * NBIN; m += 256) h[m / NBIN][m % NBIN] = 0u;
    __syncthreads();
    int sub = (tid >> 6) & 3;
    const uint4* d4 = (const uint4*)(ei + N_EDGES);
    for (long i = blockIdx.x * 256L + tid; i < N_EDGES / 4; i += (long)gridDim.x * 256) {
        uint4 d = d4[i];
        atomicAdd(&h[sub][d.x >> BINSH], 1u);
        atomicAdd(&h[sub][d.y >> BINSH], 1u);
        atomicAdd(&h[sub][d.z >> BINSH], 1u);
        atomicAdd(&h[sub][d.w >> BINSH], 1u);
    }
    __syncthreads();
    for (int m = tid; m < NBIN; m += 256) {
        unsigned int t = h[0][m] + h[1][m] + h[2][m] + h[3][m];
        if (t) atomicAdd(&bincnt[m], (int)t);
    }
}

// ---- K1b: exclusive prefix -> bin offsets + working cursors --------------
__global__ void k_prefix(const int* __restrict__ bincnt, int* __restrict__ binoff,
        int* __restrict__ bincursor) {
    if (threadIdx.x == 0) {
        int acc = 0;
        for (int b = 0; b < NBIN; ++b) {
            binoff[b] = acc; bincursor[b] = acc; acc += bincnt[b];
        }
        binoff[NBIN] = acc;   // == N_EDGES
    }
}

// ---- K2: edge messages, LDS-binned, coalesced bin-grouped writes ---------
__global__ __launch_bounds__(256) void k_scatter(const float* __restrict__ x,
        const int* __restrict__ ei, const float* __restrict__ ea,
        const float* __restrict__ We, const float* __restrict__ be,
        const int* __restrict__ binoff, int* __restrict__ bincursor,
        unsigned short* __restrict__ binidx, float* __restrict__ binmsg) {
    __shared__ unsigned int cntS[NBIN];
    __shared__ unsigned int pfxS[NBIN + 1];
    __shared__ unsigned int curS[NBIN];
    __shared__ unsigned int gbaseS[NBIN];
    __shared__ unsigned short stageI[CHUNK];
    __shared__ float stageM[CHUNK];
    __shared__ unsigned char binslot[CHUNK];
    int tid = threadIdx.x;
    long cbase = (long)blockIdx.x * CHUNK;
    for (int m = tid; m < NBIN; m += 256) cntS[m] = 0u;
    __syncthreads();
    float we0 = We[0], we1 = We[1], bcst = be[0];
    unsigned int dstR[EPT]; float msgR[EPT];
    #pragma unroll
    for (int k = 0; k < EPT; ++k) {
        long e = cbase + k * 256 + tid;
        if (e < N_EDGES) {
            int s = ei[e];
            int d = ei[N_EDGES + e];
            float2 a = ((const float2*)ea)[e];
            msgR[k] = fmaxf(x[s] + we0 * a.x + we1 * a.y + bcst, 0.f);
            dstR[k] = (unsigned int)d;
            atomicAdd(&cntS[(unsigned)d >> BINSH], 1u);
        } else {
            dstR[k] = 0xFFFFFFFFu; msgR[k] = 0.f;
        }
    }
    __syncthreads();
    if (tid == 0) {
        unsigned int acc = 0;
        for (int b = 0; b < NBIN; ++b) { pfxS[b] = acc; acc += cntS[b]; }
        pfxS[NBIN] = acc;
    }
    __syncthreads();
    if (tid < NBIN) {
        curS[tid] = pfxS[tid];
        if (cntS[tid] > 0)
            gbaseS[tid] = (unsigned int)atomicAdd(&bincursor[tid], (int)cntS[tid]);
    }
    __syncthreads();
    #pragma unroll
    for (int k = 0; k < EPT; ++k) {
        if (dstR[k] != 0xFFFFFFFFu) {
            unsigned int b = dstR[k] >> BINSH;
            unsigned int p = atomicAdd(&curS[b], 1u);
            stageI[p] = (unsigned short)(dstR[k] & (SLICE - 1));
            stageM[p] = msgR[k];
        }
    }
    if (tid < NBIN) {
        unsigned int s0 = pfxS[tid], s1 = s0 + cntS[tid];
        for (unsigned int i = s0; i < s1; ++i) binslot[i] = (unsigned char)tid;
    }
    __syncthreads();
    unsigned int tot = pfxS[NBIN];
    for (unsigned int i = tid; i < tot; i += 256) {
        unsigned int b = binslot[i];
        unsigned int g = gbaseS[b] + (i - pfxS[b]);
        binidx[g] = stageI[i];
        binmsg[g] = stageM[i];
    }
}

// ---- K2b: per-(bin,replica) LDS reduction, writes full replica slices ----
__global__ __launch_bounds__(256) void k_binagg(
        const unsigned short* __restrict__ binidx, const float* __restrict__ binmsg,
        const int* __restrict__ binoff, float* __restrict__ aggrR) {
    __shared__ float slice[SLICE];
    int bin = blockIdx.x >> 3, s = blockIdx.x & 7;
    int tid = threadIdx.x;
    for (int i = tid; i < SLICE; i += 256) slice[i] = 0.f;
    __syncthreads();
    int lo = binoff[bin], hi = binoff[bin + 1];
    long len = hi - lo;
    int a = lo + (int)((len * s) >> 3);
    int b = lo + (int)((len * (s + 1)) >> 3);
    for (int i = a + tid; i < b; i += 256)
        atomicAdd(&slice[binidx[i]], binmsg[i]);   // LDS atomic
    __syncthreads();
    int base = bin << BINSH;
    float* dst = aggrR + (size_t)s * N_NODES;
    for (int i = tid; i < SLICE; i += 256) {
        int g = base + i;
        if (g < N_NODES) dst[g] = slice[i];
    }
}

// ---- Fallback: plain-atomic edge scatter into aggrR replica 0 ------------
__global__ __launch_bounds__(256) void k_edges(const float* __restrict__ x,
        const int* __restrict__ ei, const float* __restrict__ ea,
        const float* __restrict__ We, const float* __restrict__ be,
        float* __restrict__ aggr) {
    int t = blockIdx.x * 256 + threadIdx.x;
    const int nt = N_EDGES / 4;
    if (t >= nt) return;
    float we0 = We[0], we1 = We[1], b = be[0];
    int4 s4 = ((const int4*)ei)[t];
    int4 d4 = ((const int4*)(ei + N_EDGES))[t];
    float4 a0 = ((const float4*)ea)[2 * t];
    float4 a1 = ((const float4*)ea)[2 * t + 1];
    float m0 = x[s4.x] + we0 * a0.x + we1 * a0.y + b;
    float m1 = x[s4.y] + we0 * a0.z + we1 * a0.w + b;
    float m2 = x[s4.z] + we0 * a1.x + we1 * a1.y + b;
    float m3 = x[s4.w] + we0 * a1.z + we1 * a1.w + b;
    atomicAdd(&aggr[d4.x], fmaxf(m0, 0.f));
    atomicAdd(&aggr[d4.y], fmaxf(m1, 0.f));
    atomicAdd(&aggr[d4.z], fmaxf(m2, 0.f));
    atomicAdd(&aggr[d4.w], fmaxf(m3, 0.f));
}

// ---- K3: sort breakpoints, build piecewise-linear tables A,B [257][256] --
__global__ __launch_bounds__(256) void k_table(const float* __restrict__ w1,
        const float* __restrict__ b1, const float* __restrict__ w2,
        const float* __restrict__ b2, float* __restrict__ tsort,
        float* __restrict__ A, float* __restrict__ B) {
    __shared__ float key[256];
    __shared__ int   idx[256];
    __shared__ float w1s[256], b1s[256];
    int tid = threadIdx.x;
    float w = w1[tid], bb = b1[tid];
    w1s[tid] = w; b1s[tid] = bb;
    key[tid] = (w != 0.f) ? (-bb / w) : 3.4e38f;  // w==0: never crossed
    idx[tid] = tid;
    __syncthreads();
    for (int k = 2; k <= 256; k <<= 1) {
        for (int j = k >> 1; j > 0; j >>= 1) {
            int ixj = tid ^ j;
            if (ixj > tid) {
                bool up = ((tid & k) == 0);
                float ka = key[tid], kb = key[ixj];
                if ((ka > kb) == up) {
                    key[tid] = kb; key[ixj] = ka;
                    int tmp = idx[tid]; idx[tid] = idx[ixj]; idx[ixj] = tmp;
                }
            }
            __syncthreads();
        }
    }
    tsort[tid] = key[tid];
    int f = tid;
    float a = 0.f, bv = b2[f];
    for (int k = 0; k < 256; ++k) {
        float wk = w1s[k], bk = b1s[k];
        float w2kf = w2[k * DIM + f];
        if (wk < 0.f)                       { a += wk * w2kf; bv += bk * w2kf; }
        else if (wk == 0.f && bk > 0.f)     { bv += bk * w2kf; }
    }
    A[f] = a; B[f] = bv;
    for (int j = 0; j < 256; ++j) {
        int k = idx[j];
        float wk = w1s[k], bk = b1s[k];
        float w2kf = w2[k * DIM + f];
        float cA = fabsf(wk);
        float cB = (wk > 0.f) ? bk : ((wk < 0.f) ? -bk : 0.f);
        a  += cA * w2kf;
        bv += cB * w2kf;
        A[(j + 1) * DIM + f] = a;
        B[(j + 1) * DIM + f] = bv;
    }
}

// ---- K3b: segstart[p] = lower_bound(seg, p), p in [0, N_PP] --------------
__global__ __launch_bounds__(256) void k_segstart(const int* __restrict__ seg,
        int* __restrict__ segstart) {
    int i = blockIdx.x * 256 + threadIdx.x;
    if (i >= N_NODES) return;
    int cur = seg[i];
    int prev = (i == 0) ? -1 : seg[i - 1];
    for (int p = prev + 1; p <= cur; ++p) segstart[p] = i;
    if (i == N_NODES - 1)
        for (int p = cur + 1; p <= N_PP; ++p) segstart[p] = N_NODES;
}

// ---- K4: z = x + sum(replicas), interval index, per-block histograms -----
__global__ __launch_bounds__(256) void k_stats(const float* __restrict__ x,
        const float* __restrict__ aggr8, const float* __restrict__ tsort,
        float* __restrict__ z, unsigned short* __restrict__ jidx,
        unsigned int* __restrict__ Cslab, float* __restrict__ S1slab,
        float* __restrict__ S2slab) {
    __shared__ float t[256];
    __shared__ unsigned int hc[257];
    __shared__ float h1[257], h2[257];
    int tid = threadIdx.x;
    t[tid] = tsort[tid];
    hc[tid] = 0u; h1[tid] = 0.f; h2[tid] = 0.f;
    if (tid == 0) { hc[256] = 0u; h1[256] = 0.f; h2[256] = 0.f; }
    __syncthreads();
    for (int base = blockIdx.x * 256; base < N_NODES; base += gridDim.x * 256) {
        int i = base + tid;
        bool valid = (i < N_NODES);
        float zi = 0.f;
        int lo = 0;
        if (valid) {
            zi = x[i];
            #pragma unroll
            for (int r = 0; r < RREP; ++r) zi += aggr8[(size_t)r * N_NODES + i];
            z[i] = zi;
            int l = 0, h = 256;
            while (l < h) { int mid = (l + h) >> 1; if (t[mid] <= zi) l = mid + 1; else h = mid; }
            lo = l;
            jidx[i] = (unsigned short)lo;
        }
        int lo0 = __shfl(lo, 0);
        if (__all(valid) && __all(lo == lo0)) {
            float s1 = zi, s2 = zi * zi;
            #pragma unroll
            for (int o = 32; o; o >>= 1) {
                s1 += __shfl_xor(s1, o);
                s2 += __shfl_xor(s2, o);
            }
            if ((tid & 63) == 0) {
                atomicAdd(&hc[lo0], 64u);
                atomicAdd(&h1[lo0], s1);
                atomicAdd(&h2[lo0], s2);
            }
        } else if (valid) {
            atomicAdd(&hc[lo], 1u);
            atomicAdd(&h1[lo], zi);
            atomicAdd(&h2[lo], zi * zi);
        }
    }
    __syncthreads();
    int b = blockIdx.x;
    for (int m = tid; m < 257; m += 256) {
        Cslab[b * 257 + m]  = hc[m];
        S1slab[b * 257 + m] = h1[m];
        S2slab[b * 257 + m] = h2[m];
    }
}

// ---- K5: reduce histograms, exact mean/var per feature, BN scale/shift ---
__global__ __launch_bounds__(256) void k_finalize(
        const unsigned int* __restrict__ Cslab, const float* __restrict__ S1slab,
        const float* __restrict__ S2slab, const float* __restrict__ A,
        const float* __restrict__ B, const float* __restrict__ gamma,
        const float* __restrict__ beta, float* __restrict__ scale,
        float* __restrict__ shift) {
    __shared__ double hc[257], h1[257], h2[257];
    int tid = threadIdx.x;
    for (int m = tid; m < 257; m += 256) {
        double c = 0, s1 = 0, s2 = 0;
        for (int b = 0; b < NB_STAT; ++b) {
            c  += (double)Cslab[b * 257 + m];
            s1 += (double)S1slab[b * 257 + m];
            s2 += (double)S2slab[b * 257 + m];
        }
        hc[m] = c; h1[m] = s1; h2[m] = s2;
    }
    __syncthreads();
    int f = tid;
    double mean = 0, m2 = 0;
    for (int j = 0; j <= 256; ++j) {
        double a = (double)A[j * DIM + f], b = (double)B[j * DIM + f];
        mean += a * h1[j] + b * hc[j];
        m2   += a * a * h2[j] + 2.0 * a * b * h1[j] + b * b * hc[j];
    }
    mean /= (double)N_NODES;
    double var = m2 / (double)N_NODES - mean * mean;
    float sc = gamma[f] * (float)(1.0 / sqrt(var + BN_EPS));
    scale[f] = sc;
    shift[f] = beta[f] - (float)mean * sc;
}

// ---- K6a: fill the 50000 "up" rows with up_emb ---------------------------
__global__ __launch_bounds__(256) void k_upfill(const float* __restrict__ up,
        float* __restrict__ out) {
    __shared__ float4 u4[64];
    if (threadIdx.x < 64) u4[threadIdx.x] = ((const float4*)up)[threadIdx.x];
    __syncthreads();
    const long total = (long)NUP * 64;   // float4 slots
    for (long i = blockIdx.x * 256L + threadIdx.x; i < total; i += (long)gridDim.x * 256) {
        ((float4*)out)[i] = u4[i & 63];
    }
}

// ---- K6b: per-segment pooled BN+ReLU output (segstart ranges) ------------
__global__ __launch_bounds__(256) void k_pool(const int* __restrict__ segstart,
        const float* __restrict__ z, const unsigned short* __restrict__ jidx,
        const float* __restrict__ A, const float* __restrict__ B,
        const float* __restrict__ scale, const float* __restrict__ shift,
        float* __restrict__ out) {
    int p0 = blockIdx.x * SPB;
    int f = threadIdx.x;
    float sc = scale[f], sh = shift[f];
    int i = segstart[p0];
    for (int p = p0; p < p0 + SPB; ++p) {
        int iend = segstart[p + 1];
        float acc = 0.f;
        for (; i < iend; ++i) {
            float zi = z[i];
            int j = (int)jidx[i];
            float h = sc * fmaf(A[j * DIM + f], zi, B[j * DIM + f]) + sh;
            acc += fmaxf(h, 0.f);
        }
        out[(long)(NUP + p) * DIM + f] = acc;
    }
}

extern "C" void kernel_launch(void* const* d_in, const int* in_sizes, int n_in,
                              void* d_out, int out_size, void* d_ws, size_t ws_size,
                              hipStream_t stream) {
    const float* x     = (const float*)d_in[0];
    const int*   ei    = (const int*)d_in[1];
    const float* ea    = (const float*)d_in[2];
    const int*   seg   = (const int*)d_in[3];
    // d_in[4] = total_edges (fixed 150000 by setup)
    const float* We    = (const float*)d_in[5];
    const float* be    = (const float*)d_in[6];
    const float* w1    = (const float*)d_in[7];
    const float* b1    = (const float*)d_in[8];
    const float* w2    = (const float*)d_in[9];
    const float* b2    = (const float*)d_in[10];
    const float* gamma = (const float*)d_in[11];
    const float* beta  = (const float*)d_in[12];
    const float* up    = (const float*)d_in[13];
    float* out = (float*)d_out;

    char* ws = (char*)d_ws;
    size_t off = 0;
    auto carve = [&](size_t bytes) -> void* {
        void* p = ws + off;
        off = (off + bytes + 255) & ~(size_t)255;
        return p;
    };
    // small/common buffers first (~23 MB incl. aggrR — proven to fit)
    float*          aggrR  = (float*)carve((size_t)RREP * N_NODES * 4);   // 16 MB
    float*          zbuf   = (float*)carve(N_NODES * 4);
    unsigned short* jidx   = (unsigned short*)carve(N_NODES * 2);
    int*            segst  = (int*)carve((N_PP + 1) * 4);
    int*            bincnt = (int*)carve(NBIN * 4);
    int*            binoff = (int*)carve((NBIN + 1) * 4);
    int*            bincur = (int*)carve(NBIN * 4);
    float*          tsort  = (float*)carve(256 * 4);
    float*          A      = (float*)carve(257 * DIM * 4);
    float*          B      = (float*)carve(257 * DIM * 4);
    unsigned int*   Cslab  = (unsigned int*)carve(NB_STAT * 257 * 4);
    float*          S1slab = (float*)carve(NB_STAT * 257 * 4);
    float*          S2slab = (float*)carve(NB_STAT * 257 * 4);
    float*          scale  = (float*)carve(256 * 4);
    float*          shift  = (float*)carve(256 * 4);
    // large binning buffers last; take the binning path only if they fit
    size_t need_big = (size_t)N_EDGES * 2 + 256 + (size_t)N_EDGES * 4 + 256;
    bool use_bin = (off + need_big) <= ws_size;
    unsigned short* binidx = nullptr;
    float*          binmsg = nullptr;
    if (use_bin) {
        binidx = (unsigned short*)carve((size_t)N_EDGES * 2);             // 16 MB
        binmsg = (float*)carve((size_t)N_EDGES * 4);                      // 32 MB
    }

    if (use_bin) {
        hipMemsetAsync(bincnt, 0, NBIN * 4, stream);
        k_count<<<512, 256, 0, stream>>>(ei, bincnt);
        k_prefix<<<1, 64, 0, stream>>>(bincnt, binoff, bincur);
        k_scatter<<<(N_EDGES + CHUNK - 1) / CHUNK, 256, 0, stream>>>(
            x, ei, ea, We, be, binoff, bincur, binidx, binmsg);
        k_binagg<<<NBIN * RREP, 256, 0, stream>>>(binidx, binmsg, binoff, aggrR);
    } else {
        hipMemsetAsync(aggrR, 0, (size_t)RREP * N_NODES * 4, stream);
        k_edges<<<(N_EDGES / 4 + 255) / 256, 256, 0, stream>>>(x, ei, ea, We, be, aggrR);
    }
    k_table<<<1, 256, 0, stream>>>(w1, b1, w2, b2, tsort, A, B);
    k_segstart<<<(N_NODES + 255) / 256, 256, 0, stream>>>(seg, segst);
    k_stats<<<NB_STAT, 256, 0, stream>>>(x, aggrR, tsort, zbuf, jidx, Cslab, S1slab, S2slab);
    k_finalize<<<1, 256, 0, stream>>>(Cslab, S1slab, S2slab, A, B, gamma, beta, scale, shift);
    k_upfill<<<2048, 256, 0, stream>>>(up, out);
    k_pool<<<N_PP / SPB, 256, 0, stream>>>(segst, zbuf, jidx, A, B, scale, shift, out);
}